// Round 1
// baseline (360.994 us; speedup 1.0000x reference)
//
#include <hip/hip_runtime.h>
#include <hip/hip_bf16.h>

// MultiHeadAttention: x(2,2048,1024) fp32 -> out(2,2048,1024) fp32
// Pipeline: cvt->bf16; QKV GEMM (mfma bf16) -> q(*0.125),k,v^T; flash attn; out GEMM.

typedef __bf16 bf16x8 __attribute__((ext_vector_type(8)));
typedef float f32x4 __attribute__((ext_vector_type(4)));

__device__ __forceinline__ unsigned short f2bf(float f) {
    union { float f; unsigned int u; } v; v.f = f;
    return (unsigned short)((v.u + 0x7FFFu + ((v.u >> 16) & 1u)) >> 16);
}

__global__ void cvt_f32_bf16_v4(const float4* __restrict__ src,
                                ushort4* __restrict__ dst, int n4) {
    int i = blockIdx.x * blockDim.x + threadIdx.x;
    int stride = gridDim.x * blockDim.x;
    for (; i < n4; i += stride) {
        float4 f = src[i];
        ushort4 o;
        o.x = f2bf(f.x); o.y = f2bf(f.y); o.z = f2bf(f.z); o.w = f2bf(f.w);
        dst[i] = o;
    }
}

// C = A(M x 1024) @ W(N x 1024)^T + bias. 128x128 block tile, 4 waves (2x2) of 64x64.
// MODE 0: N=3072, scatter to q (scaled 0.125), k, vt (v transposed [bh][dk][n]) as bf16.
// MODE 1: N=1024, fp32 out row-major.
template<int MODE>
__global__ __launch_bounds__(256) void gemm_mfma(
    const unsigned short* __restrict__ A,
    const unsigned short* __restrict__ W,
    const float* __restrict__ bias,
    unsigned short* __restrict__ qo,
    unsigned short* __restrict__ ko,
    unsigned short* __restrict__ vto,
    float* __restrict__ fo) {
    const int lane = threadIdx.x & 63;
    const int wave = threadIdx.x >> 6;
    const int g = lane >> 4, c = lane & 15;
    const int wr = wave >> 1, wc = wave & 1;
    const int row0 = blockIdx.x * 128 + wr * 64;
    const int col0 = blockIdx.y * 128 + wc * 64;

    f32x4 acc[4][4] = {};
    const unsigned short* Ab = A + (size_t)(row0 + c) * 1024 + 8 * g;
    const unsigned short* Wb = W + (size_t)(col0 + c) * 1024 + 8 * g;

    for (int kk = 0; kk < 1024; kk += 32) {
        bf16x8 a[4], b[4];
        #pragma unroll
        for (int mi = 0; mi < 4; ++mi)
            a[mi] = *(const bf16x8*)(Ab + mi * 16 * 1024 + kk);
        #pragma unroll
        for (int ni = 0; ni < 4; ++ni)
            b[ni] = *(const bf16x8*)(Wb + ni * 16 * 1024 + kk);
        #pragma unroll
        for (int mi = 0; mi < 4; ++mi) {
            #pragma unroll
            for (int ni = 0; ni < 4; ++ni)
                acc[mi][ni] = __builtin_amdgcn_mfma_f32_16x16x32_bf16(
                    a[mi], b[ni], acc[mi][ni], 0, 0, 0);
        }
    }

    #pragma unroll
    for (int mi = 0; mi < 4; ++mi) {
        #pragma unroll
        for (int ni = 0; ni < 4; ++ni) {
            const int col = col0 + ni * 16 + c;
            const float bv = bias[col];
            #pragma unroll
            for (int j = 0; j < 4; ++j) {
                const int row = row0 + mi * 16 + 4 * g + j;
                float v = acc[mi][ni][j] + bv;
                if (MODE == 1) {
                    fo[(size_t)row * 1024 + col] = v;
                } else {
                    const int sec = col >> 10;          // 0=q 1=k 2=v
                    const int d = col & 1023;
                    const int h = d >> 6, dk = d & 63;
                    const int b_ = row >> 11, n = row & 2047;
                    const int bh = b_ * 16 + h;
                    if (sec == 0)
                        qo[((size_t)(bh * 2048 + n) << 6) + dk] = f2bf(v * 0.125f);
                    else if (sec == 1)
                        ko[((size_t)(bh * 2048 + n) << 6) + dk] = f2bf(v);
                    else
                        vto[(size_t)(bh * 64 + dk) * 2048 + n] = f2bf(v);
                }
            }
        }
    }
}

// Flash attention. Q,K: [32][2048][64] bf16 (Q pre-scaled). Vt: [32][64][2048] bf16.
// O: [4096][1024] bf16 (row = b*2048+n, col = h*64+dk).
// Block: 4 waves, each owns 32 q-rows; loop kv in tiles of 64.
__global__ __launch_bounds__(256) void attn_flash(
    const unsigned short* __restrict__ Q,
    const unsigned short* __restrict__ K,
    const unsigned short* __restrict__ Vt,
    unsigned short* __restrict__ O) {
    __shared__ __attribute__((aligned(16))) unsigned short P_lds[4][32][72];
    const int lane = threadIdx.x & 63;
    const int w = threadIdx.x >> 6;
    const int g = lane >> 4, c = lane & 15;
    const int bh = blockIdx.y;
    const int q0 = blockIdx.x * 128 + w * 32;
    const unsigned short* Qb = Q + (size_t)bh * 2048 * 64;
    const unsigned short* Kb = K + (size_t)bh * 2048 * 64;
    const unsigned short* Vb = Vt + (size_t)bh * 64 * 2048;

    bf16x8 aq[2][2];
    #pragma unroll
    for (int mi = 0; mi < 2; ++mi) {
        #pragma unroll
        for (int ks = 0; ks < 2; ++ks)
            aq[mi][ks] = *(const bf16x8*)(Qb + (size_t)(q0 + mi * 16 + c) * 64 + ks * 32 + 8 * g);
    }

    f32x4 o[2][4] = {};
    float m_run[2][4], l_run[2][4];
    #pragma unroll
    for (int mi = 0; mi < 2; ++mi) {
        #pragma unroll
        for (int j = 0; j < 4; ++j) { m_run[mi][j] = -1e30f; l_run[mi][j] = 0.f; }
    }

    for (int kv = 0; kv < 2048; kv += 64) {
        f32x4 s[2][4] = {};
        #pragma unroll
        for (int nj = 0; nj < 4; ++nj) {
            #pragma unroll
            for (int ks = 0; ks < 2; ++ks) {
                bf16x8 bk = *(const bf16x8*)(Kb + (size_t)(kv + nj * 16 + c) * 64 + ks * 32 + 8 * g);
                #pragma unroll
                for (int mi = 0; mi < 2; ++mi)
                    s[mi][nj] = __builtin_amdgcn_mfma_f32_16x16x32_bf16(
                        aq[mi][ks], bk, s[mi][nj], 0, 0, 0);
            }
        }
        // online softmax (rows live in 16-lane groups: row=4*g+j within 16-tile, col=c)
        float sc[2][4];
        #pragma unroll
        for (int mi = 0; mi < 2; ++mi) {
            #pragma unroll
            for (int j = 0; j < 4; ++j) {
                float mx = fmaxf(fmaxf(s[mi][0][j], s[mi][1][j]),
                                 fmaxf(s[mi][2][j], s[mi][3][j]));
                #pragma unroll
                for (int msk = 1; msk <= 8; msk <<= 1)
                    mx = fmaxf(mx, __shfl_xor(mx, msk));
                const float mnew = fmaxf(m_run[mi][j], mx);
                sc[mi][j] = __expf(m_run[mi][j] - mnew);
                m_run[mi][j] = mnew;
                float rs = 0.f;
                #pragma unroll
                for (int nj = 0; nj < 4; ++nj) {
                    float p = __expf(s[mi][nj][j] - mnew);
                    s[mi][nj][j] = p;
                    rs += p;
                }
                #pragma unroll
                for (int msk = 1; msk <= 8; msk <<= 1)
                    rs += __shfl_xor(rs, msk);
                l_run[mi][j] = l_run[mi][j] * sc[mi][j] + rs;
            }
        }
        #pragma unroll
        for (int mi = 0; mi < 2; ++mi) {
            #pragma unroll
            for (int ni = 0; ni < 4; ++ni) {
                #pragma unroll
                for (int j = 0; j < 4; ++j)
                    o[mi][ni][j] *= sc[mi][j];
            }
        }
        // P -> LDS (C/D layout) then reload as A-fragments
        #pragma unroll
        for (int mi = 0; mi < 2; ++mi) {
            #pragma unroll
            for (int nj = 0; nj < 4; ++nj) {
                #pragma unroll
                for (int j = 0; j < 4; ++j)
                    P_lds[w][mi * 16 + 4 * g + j][nj * 16 + c] = f2bf(s[mi][nj][j]);
            }
        }
        #pragma unroll
        for (int ks = 0; ks < 2; ++ks) {
            bf16x8 ap[2];
            #pragma unroll
            for (int mi = 0; mi < 2; ++mi)
                ap[mi] = *(const bf16x8*)&P_lds[w][mi * 16 + c][ks * 32 + 8 * g];
            #pragma unroll
            for (int ni = 0; ni < 4; ++ni) {
                bf16x8 bv = *(const bf16x8*)(Vb + (size_t)(ni * 16 + c) * 2048 + kv + ks * 32 + 8 * g);
                #pragma unroll
                for (int mi = 0; mi < 2; ++mi)
                    o[mi][ni] = __builtin_amdgcn_mfma_f32_16x16x32_bf16(
                        ap[mi], bv, o[mi][ni], 0, 0, 0);
            }
        }
    }

    const int b_ = bh >> 4, h = bh & 15;
    #pragma unroll
    for (int mi = 0; mi < 2; ++mi) {
        #pragma unroll
        for (int ni = 0; ni < 4; ++ni) {
            #pragma unroll
            for (int j = 0; j < 4; ++j) {
                const int row = b_ * 2048 + q0 + mi * 16 + 4 * g + j;
                const int col = h * 64 + ni * 16 + c;
                O[(size_t)row * 1024 + col] = f2bf(o[mi][ni][j] / l_run[mi][j]);
            }
        }
    }
}

extern "C" void kernel_launch(void* const* d_in, const int* in_sizes, int n_in,
                              void* d_out, int out_size, void* d_ws, size_t ws_size,
                              hipStream_t stream) {
    const float* x     = (const float*)d_in[0];
    const float* qkv_w = (const float*)d_in[1];
    const float* qkv_b = (const float*)d_in[2];
    const float* out_w = (const float*)d_in[3];
    const float* out_b = (const float*)d_in[4];
    float* out = (float*)d_out;

    char* ws = (char*)d_ws;
    unsigned short* xb   = (unsigned short*)(ws);              //  8 MB (reused as attn-out)
    unsigned short* wqkv = (unsigned short*)(ws + (8u  << 20)); //  6 MB
    unsigned short* wout = (unsigned short*)(ws + (14u << 20)); //  2 MB
    unsigned short* qb   = (unsigned short*)(ws + (16u << 20)); //  8 MB
    unsigned short* kb   = (unsigned short*)(ws + (24u << 20)); //  8 MB
    unsigned short* vtb  = (unsigned short*)(ws + (32u << 20)); //  8 MB  (total 40 MB)

    cvt_f32_bf16_v4<<<2048, 256, 0, stream>>>((const float4*)x,     (ushort4*)xb,   4096 * 1024 / 4);
    cvt_f32_bf16_v4<<<2048, 256, 0, stream>>>((const float4*)qkv_w, (ushort4*)wqkv, 3072 * 1024 / 4);
    cvt_f32_bf16_v4<<<1024, 256, 0, stream>>>((const float4*)out_w, (ushort4*)wout, 1024 * 1024 / 4);

    gemm_mfma<0><<<dim3(32, 24), 256, 0, stream>>>(xb, wqkv, qkv_b, qb, kb, vtb, nullptr);

    unsigned short* ao = xb;  // xb no longer needed; reuse for attention output
    attn_flash<<<dim3(16, 32), 256, 0, stream>>>(qb, kb, vtb, ao);

    gemm_mfma<1><<<dim3(32, 8), 256, 0, stream>>>(ao, wout, out_b, nullptr, nullptr, nullptr, out);
}